// Round 10
// baseline (774.776 us; speedup 1.0000x reference)
//
#include <hip/hip_runtime.h>
#include <hip/hip_bf16.h>
#include <math.h>

#define NUM_HEADS 12
#define N_TOK 197
#define C_DIM 768
#define B_SZ 64
#define M_ROWS (B_SZ * N_TOK)     /* 12608 */
#define QKV_COLS (3 * C_DIM)      /* 2304  */
#define NN (N_TOK * N_TOK)        /* 38809 */
#define VT_PITCH 232              /* bf16 units */

typedef __hip_bfloat16 bf16;
typedef __attribute__((ext_vector_type(8))) short short8;
typedef __attribute__((ext_vector_type(4))) float floatx4;
typedef unsigned long long u64;

__device__ __forceinline__ void split2(float x, short& hi, short& lo) {
    bf16 h = __float2bfloat16(x);
    float hf = __bfloat162float(h);
    bf16 l = __float2bfloat16(x - hf);
    hi = __builtin_bit_cast(short, h);
    lo = __builtin_bit_cast(short, l);
}

__device__ __forceinline__ void split3(float x, short& s0, short& s1, short& s2) {
    bf16 h = __float2bfloat16(x);
    float r1 = x - __bfloat162float(h);          // exact
    bf16 m = __float2bfloat16(r1);
    float r2 = r1 - __bfloat162float(m);         // exact
    bf16 l = __float2bfloat16(r2);               // exact (<=8 significant bits left)
    s0 = __builtin_bit_cast(short, h);
    s1 = __builtin_bit_cast(short, m);
    s2 = __builtin_bit_cast(short, l);
}

// ---------------------------------------------------------------------------
// fp32-exact-split GEMM: C = A @ B^T (+bias). 3-way bf16 split (exact 24-bit
// decomposition), 6 MFMA terms in fixed order -> bit-identical accumulation
// to the R7/R9-proven kernel. 256x128 block, each wave 128x64, BK=32.
// B-fragments hoisted; af loaded per split-plane. LDS 73.7 KB -> 2 blocks/CU.
// ---------------------------------------------------------------------------
template<bool ADD_BIAS>
__global__ __launch_bounds__(256) void gemm_split6(
    const float* __restrict__ A, const float* __restrict__ B,
    const float* __restrict__ bias, float* __restrict__ C,
    int M, int N, int K)
{
    __shared__ short8 As[3][1024];   // [plane][quad*256 + row]  48 KB
    __shared__ short8 Bs[3][512];    // [plane][quad*128 + row]  24 KB
    const int t = threadIdx.x;
    const int tile_m = blockIdx.y * 256;
    const int tile_n = blockIdx.x * 128;
    const int wave = t >> 6, lane = t & 63;
    const int quad = lane >> 4, mrow = lane & 15;
    const int wr = (wave >> 1) * 128, wc = (wave & 1) * 64;

    floatx4 acc[8][4];
#pragma unroll
    for (int i = 0; i < 8; ++i)
#pragma unroll
        for (int j = 0; j < 4; ++j) acc[i][j] = (floatx4){0.f, 0.f, 0.f, 0.f};

    for (int k0 = 0; k0 < K; k0 += 32) {
        __syncthreads();
        // stage A: 1024 8-element groups
#pragma unroll
        for (int s = 0; s < 4; ++s) {
            int g = s * 256 + t;
            int row = g >> 2, q = g & 3;
            int ga = tile_m + row;
            float4 a0 = {0.f, 0.f, 0.f, 0.f}, a1 = {0.f, 0.f, 0.f, 0.f};
            if (ga < M) {
                const float* p = A + (size_t)ga * K + k0 + q * 8;
                a0 = *(const float4*)p;
                a1 = *(const float4*)(p + 4);
            }
            float xs[8] = {a0.x, a0.y, a0.z, a0.w, a1.x, a1.y, a1.z, a1.w};
            short8 v0, v1, v2;
#pragma unroll
            for (int e = 0; e < 8; ++e) {
                short h, m, l; split3(xs[e], h, m, l);
                v0[e] = h; v1[e] = m; v2[e] = l;
            }
            As[0][q * 256 + row] = v0;
            As[1][q * 256 + row] = v1;
            As[2][q * 256 + row] = v2;
        }
        // stage B: 512 groups (always in-bounds for N=2304/768 grids)
#pragma unroll
        for (int s = 0; s < 2; ++s) {
            int g = s * 256 + t;
            int row = g >> 2, q = g & 3;
            const float* p = B + (size_t)(tile_n + row) * K + k0 + q * 8;
            float4 b0 = *(const float4*)p;
            float4 b1 = *(const float4*)(p + 4);
            float xs[8] = {b0.x, b0.y, b0.z, b0.w, b1.x, b1.y, b1.z, b1.w};
            short8 v0, v1, v2;
#pragma unroll
            for (int e = 0; e < 8; ++e) {
                short h, m, l; split3(xs[e], h, m, l);
                v0[e] = h; v1[e] = m; v2[e] = l;
            }
            Bs[0][q * 128 + row] = v0;
            Bs[1][q * 128 + row] = v1;
            Bs[2][q * 128 + row] = v2;
        }
        __syncthreads();

        short8 bfr[3][4];
#pragma unroll
        for (int tb = 0; tb < 3; ++tb)
#pragma unroll
            for (int j = 0; j < 4; ++j)
                bfr[tb][j] = Bs[tb][quad * 128 + wc + j * 16 + mrow];

#pragma unroll
        for (int ta = 0; ta < 3; ++ta) {
            short8 af[8];
#pragma unroll
            for (int i = 0; i < 8; ++i)
                af[i] = As[ta][quad * 256 + wr + i * 16 + mrow];
            const int ntb = 3 - ta;   // term order: (0,0)(0,1)(0,2)(1,0)(1,1)(2,0)
#pragma unroll
            for (int tb = 0; tb < 3; ++tb) {
                if (tb >= ntb) break;
#pragma unroll
                for (int i = 0; i < 8; ++i)
#pragma unroll
                    for (int j = 0; j < 4; ++j)
                        acc[i][j] = __builtin_amdgcn_mfma_f32_16x16x32_bf16(af[i], bfr[tb][j], acc[i][j], 0, 0, 0);
            }
        }
    }

#pragma unroll
    for (int i = 0; i < 8; ++i)
#pragma unroll
        for (int r = 0; r < 4; ++r) {
            int grow = tile_m + wr + i * 16 + quad * 4 + r;
            if (grow < M)
#pragma unroll
                for (int j = 0; j < 4; ++j) {
                    int gcol = tile_n + wc + j * 16 + mrow;
                    float v = acc[i][j][r];
                    if (ADD_BIAS) v += bias[gcol];
                    C[(size_t)grow * N + gcol] = v;
                }
        }
}

// ---------------------------------------------------------------------------
// Per-(b,h): s_q, s_k (f64 means), sv = 127.f/(m+1e-6f) np-exact, sign bits.
// ---------------------------------------------------------------------------
__global__ __launch_bounds__(256) void quant_stats(
    const float* __restrict__ qkv, float* __restrict__ sqf, float* __restrict__ skf,
    u64* __restrict__ qbits, u64* __restrict__ kbits, float* __restrict__ svf)
{
    const int bh = blockIdx.x;
    const int b = bh / NUM_HEADS, h = bh % NUM_HEADS;
    const int t = threadIdx.x;
    const size_t base = (size_t)b * N_TOK * QKV_COLS + h * 64;
    __shared__ double red[256];
    __shared__ float redf[256];

    const int d = t & 63;
    double aq = 0.0, ak = 0.0;
    for (int i = t; i < N_TOK * 64; i += 256) {
        int n = i >> 6;
        size_t off = base + (size_t)n * QKV_COLS + d;
        aq += (double)fabsf(qkv[off]);
        ak += (double)fabsf(qkv[off + C_DIM]);
    }
    red[t] = aq; __syncthreads();
    for (int s = 128; s > 0; s >>= 1) { if (t < s) red[t] += red[t + s]; __syncthreads(); }
    if (t == 0) sqf[bh] = (float)(red[0] / 12608.0);
    __syncthreads();
    red[t] = ak; __syncthreads();
    for (int s = 128; s > 0; s >>= 1) { if (t < s) red[t] += red[t + s]; __syncthreads(); }
    if (t == 0) skf[bh] = (float)(red[0] / 12608.0);
    __syncthreads();

    float vm = 0.f;
    for (int n = (t >> 6); n < N_TOK; n += 4)
        vm = fmaxf(vm, fabsf(qkv[base + (size_t)n * QKV_COLS + 2 * C_DIM + d]));
    redf[t] = vm; __syncthreads();
    if (t < 64) {
        float m4 = fmaxf(fmaxf(redf[t], redf[t + 64]), fmaxf(redf[t + 128], redf[t + 192]));
        svf[bh * 64 + t] = 127.0f / (m4 + 1e-6f);
    }

    const int wave = t >> 6, lane = t & 63;
    for (int n = wave; n < N_TOK; n += 4) {
        size_t off = base + (size_t)n * QKV_COLS + lane;
        u64 bq = __ballot(qkv[off] >= 0.f);
        u64 bk = __ballot(qkv[off + C_DIM] >= 0.f);
        if (lane == 0) { qbits[bh * N_TOK + n] = bq; kbits[bh * N_TOK + n] = bk; }
    }
}

__global__ void detect_rel64(const int* __restrict__ rel, int* __restrict__ flag)
{
    __shared__ int nz;
    if (threadIdx.x == 0) nz = 0;
    __syncthreads();
    int local = 0;
    for (int i = threadIdx.x; i < NN / 2; i += 256)
        if (rel[2 * i + 1] != 0) local = 1;
    if (local) atomicOr(&nz, 1);
    __syncthreads();
    if (threadIdx.x == 0) flag[0] = (nz == 0) ? 1 : 0;
}

__global__ void build_bias(const float* __restrict__ rpb, const int* __restrict__ rel,
                           const int* __restrict__ flag, float* __restrict__ bias_f)
{
    int nm = blockIdx.x * 256 + threadIdx.x;
    int h = blockIdx.y;
    if (nm < NN) {
        int idx = flag[0] ? rel[2 * nm] : rel[nm];
        bias_f[(size_t)h * NN + nm] = rpb[idx * NUM_HEADS + h];
    }
}

// ---------------------------------------------------------------------------
// Fused attention with MFMA P@V (R9-proven, unchanged).
// ---------------------------------------------------------------------------
__global__ __launch_bounds__(256) void attn_mfma(
    const float* __restrict__ qkv, const float* __restrict__ sqf, const float* __restrict__ skf,
    const u64* __restrict__ qbits, const u64* __restrict__ kbits,
    const float* __restrict__ svf, const float* __restrict__ bias_f,
    float* __restrict__ attn_out)
{
    const int bh = blockIdx.x;
    const int b = bh / NUM_HEADS, h = bh % NUM_HEADS;
    const int t = threadIdx.x;
    const int wave = t >> 6, lane = t & 63;
    const int quad = lane >> 4, mrow = lane & 15;

    __shared__ __align__(16) short vth[64 * VT_PITCH];
    __shared__ __align__(16) short vtl[64 * VT_PITCH];
    __shared__ __align__(16) short pbuf[2][16 * VT_PITCH];
    __shared__ u64 qb[N_TOK], kb[N_TOK];

    for (int i = t; i < N_TOK; i += 256) {
        qb[i] = qbits[bh * N_TOK + i];
        kb[i] = kbits[bh * N_TOK + i];
    }

    const size_t vbase = (size_t)b * N_TOK * QKV_COLS + 2 * C_DIM + h * 64;
    const int d0 = t & 63;
    const float sv = svf[bh * 64 + d0];
    const float inv_sv = sv + 1e-6f;
    for (int i = t; i < N_TOK * 64; i += 256) {
        int n = i >> 6;
        float v = qkv[vbase + (size_t)n * QKV_COLS + d0];
        float vqf = rintf(v * sv) / inv_sv;
        short hh, ll; split2(vqf, hh, ll);
        vth[d0 * VT_PITCH + n] = hh;
        vtl[d0 * VT_PITCH + n] = ll;
    }
    for (int i = t; i < 64 * (VT_PITCH - N_TOK); i += 256) {
        int d = i / (VT_PITCH - N_TOK), n = N_TOK + i % (VT_PITCH - N_TOK);
        vth[d * VT_PITCH + n] = 0;
        vtl[d * VT_PITCH + n] = 0;
    }
    __syncthreads();

    const int ct = wave;
    short8 bfh[7], bfl[7];
#pragma unroll
    for (int kt = 0; kt < 7; ++kt) {
        int off = (ct * 16 + mrow) * VT_PITCH + kt * 32 + quad * 8;
        bfh[kt] = *(const short8*)&vth[off];
        bfl[kt] = *(const short8*)&vtl[off];
    }

    const float cf = sqf[bh] * skf[bh] * 0.125f;
    const float* bh_bias = bias_f + (size_t)h * NN;
    const float qs = 1.0f / 255.0f;

    auto computeP = [&](int strip, int buf) {
        short* pb = &pbuf[buf][0];
#pragma unroll
        for (int rr = 0; rr < 4; ++rr) {
            int nl = wave * 4 + rr;
            int n = strip * 16 + nl;
            short* prow = pb + nl * VT_PITCH;
            int m0 = lane, m1 = 64 + lane, m2 = 128 + lane, m3 = 192 + lane;
            if (n < N_TOK) {
                const u64 qn = qb[n];
                const float* brow = bh_bias + (size_t)n * N_TOK;
                float l0 = cf * (float)(64 - 2 * (int)__popcll(qn ^ kb[m0])) + brow[m0];
                float l1 = cf * (float)(64 - 2 * (int)__popcll(qn ^ kb[m1])) + brow[m1];
                float l2 = cf * (float)(64 - 2 * (int)__popcll(qn ^ kb[m2])) + brow[m2];
                float l3 = -1e30f;
                if (m3 < N_TOK)
                    l3 = cf * (float)(64 - 2 * (int)__popcll(qn ^ kb[m3])) + brow[m3];
                float mx = fmaxf(fmaxf(l0, l1), fmaxf(l2, l3));
#pragma unroll
                for (int off = 32; off > 0; off >>= 1) mx = fmaxf(mx, __shfl_xor(mx, off, 64));
                float e0 = expf(l0 - mx), e1 = expf(l1 - mx), e2 = expf(l2 - mx);
                float e3 = (m3 < N_TOK) ? expf(l3 - mx) : 0.f;
                float sum = e0 + e1 + e2 + e3;
#pragma unroll
                for (int off = 32; off > 0; off >>= 1) sum += __shfl_xor(sum, off, 64);
                float inv = 1.0f / sum;
                float p0 = fminf(rintf((e0 * inv) / qs), 255.f);
                float p1 = fminf(rintf((e1 * inv) / qs), 255.f);
                float p2 = fminf(rintf((e2 * inv) / qs), 255.f);
                float p3 = fminf(rintf((e3 * inv) / qs), 255.f);
                prow[m0] = __builtin_bit_cast(short, __float2bfloat16(p0));
                prow[m1] = __builtin_bit_cast(short, __float2bfloat16(p1));
                prow[m2] = __builtin_bit_cast(short, __float2bfloat16(p2));
                if (m3 < VT_PITCH)
                    prow[m3] = __builtin_bit_cast(short, __float2bfloat16(p3));
            } else {
                prow[m0] = 0; prow[m1] = 0; prow[m2] = 0;
                if (m3 < VT_PITCH) prow[m3] = 0;
            }
        }
    };

    computeP(0, 0);
    __syncthreads();

    for (int strip = 0; strip < 13; ++strip) {
        if (strip + 1 < 13) computeP(strip + 1, (strip + 1) & 1);

        const short* pb = &pbuf[strip & 1][0];
        floatx4 acc = (floatx4){0.f, 0.f, 0.f, 0.f};
#pragma unroll
        for (int kt = 0; kt < 7; ++kt) {
            short8 af = *(const short8*)&pb[mrow * VT_PITCH + kt * 32 + quad * 8];
            acc = __builtin_amdgcn_mfma_f32_16x16x32_bf16(af, bfh[kt], acc, 0, 0, 0);
            acc = __builtin_amdgcn_mfma_f32_16x16x32_bf16(af, bfl[kt], acc, 0, 0, 0);
        }
#pragma unroll
        for (int r = 0; r < 4; ++r) {
            int n = strip * 16 + quad * 4 + r;
            if (n < N_TOK)
                attn_out[((size_t)(b * N_TOK + n)) * C_DIM + h * 64 + ct * 16 + mrow] = qs * acc[r];
        }
        __syncthreads();
    }
}

// ---------------------------------------------------------------------------
extern "C" void kernel_launch(void* const* d_in, const int* in_sizes, int n_in,
                              void* d_out, int out_size, void* d_ws, size_t ws_size,
                              hipStream_t stream)
{
    const float* x      = (const float*)d_in[0];
    const float* w_qkv  = (const float*)d_in[1];
    const float* w_proj = (const float*)d_in[2];
    const float* b_proj = (const float*)d_in[3];
    const float* rpb    = (const float*)d_in[4];
    const int*   rel    = (const int*)d_in[5];
    float* out = (float*)d_out;

    char* ws = (char*)d_ws;
    float* qkv     = (float*)ws; ws += (size_t)M_ROWS * QKV_COLS * sizeof(float);
    float* attn_o  = (float*)ws; ws += (size_t)M_ROWS * C_DIM * sizeof(float);
    float* bias_f  = (float*)ws; ws += (size_t)NUM_HEADS * NN * sizeof(float);
    float* sqf     = (float*)ws; ws += 768 * sizeof(float);
    float* skf     = (float*)ws; ws += 768 * sizeof(float);
    float* svf     = (float*)ws; ws += 768 * 64 * sizeof(float);
    u64* qbits     = (u64*)ws;   ws += (size_t)768 * N_TOK * sizeof(u64);
    u64* kbits     = (u64*)ws;   ws += (size_t)768 * N_TOK * sizeof(u64);
    int* flag      = (int*)ws;   ws += 256;

    detect_rel64<<<1, 256, 0, stream>>>(rel, flag);

    // 1) QKV: 256x128 blocks, grid 18 x 50
    gemm_split6<false><<<dim3(QKV_COLS / 128, (M_ROWS + 255) / 256), 256, 0, stream>>>(
        x, w_qkv, nullptr, qkv, M_ROWS, QKV_COLS, C_DIM);

    quant_stats<<<768, 256, 0, stream>>>(qkv, sqf, skf, qbits, kbits, svf);

    build_bias<<<dim3((NN + 255) / 256, NUM_HEADS), 256, 0, stream>>>(rpb, rel, flag, bias_f);

    attn_mfma<<<768, 256, 0, stream>>>(qkv, sqf, skf, qbits, kbits, svf, bias_f, attn_o);

    // 5) proj: same exact-split kernel, grid 6 x 50
    gemm_split6<true><<<dim3(C_DIM / 128, (M_ROWS + 255) / 256), 256, 0, stream>>>(
        attn_o, w_proj, b_proj, out, M_ROWS, C_DIM, C_DIM);
}

// Round 11
// 678.257 us; speedup vs baseline: 1.1423x; 1.1423x over previous
//
#include <hip/hip_runtime.h>
#include <hip/hip_bf16.h>
#include <math.h>

#define NUM_HEADS 12
#define N_TOK 197
#define C_DIM 768
#define B_SZ 64
#define M_ROWS (B_SZ * N_TOK)     /* 12608 */
#define QKV_COLS (3 * C_DIM)      /* 2304  */
#define NN (N_TOK * N_TOK)        /* 38809 */
#define VT_PITCH 232

typedef __hip_bfloat16 bf16;
typedef __attribute__((ext_vector_type(8))) short short8;
typedef __attribute__((ext_vector_type(4))) short short4v;
typedef __attribute__((ext_vector_type(4))) float floatx4;
typedef unsigned long long u64;

__device__ __forceinline__ void split2(float x, short& hi, short& lo) {
    bf16 h = __float2bfloat16(x);
    float hf = __bfloat162float(h);
    bf16 l = __float2bfloat16(x - hf);
    hi = __builtin_bit_cast(short, h);
    lo = __builtin_bit_cast(short, l);
}

// round-based 3-way split (R7-proven) — used for one-time weight presplit
__device__ __forceinline__ void split3(float x, short& s0, short& s1, short& s2) {
    bf16 h = __float2bfloat16(x);
    float r1 = x - __bfloat162float(h);
    bf16 m = __float2bfloat16(r1);
    float r2 = r1 - __bfloat162float(m);
    bf16 l = __float2bfloat16(r2);
    s0 = __builtin_bit_cast(short, h);
    s1 = __builtin_bit_cast(short, m);
    s2 = __builtin_bit_cast(short, l);
}

// truncation 3-way split: exact 8+8+8-bit decomposition (sum == x), cheap VALU
__device__ __forceinline__ void tsplit3(float x, short& s0, short& s1, short& s2) {
    unsigned u = __builtin_bit_cast(unsigned, x);
    s0 = (short)(u >> 16);
    float r1 = x - __builtin_bit_cast(float, u & 0xFFFF0000u);   // exact
    unsigned u1 = __builtin_bit_cast(unsigned, r1);
    s1 = (short)(u1 >> 16);
    float r2 = r1 - __builtin_bit_cast(float, u1 & 0xFFFF0000u); // exact, <=8 sig bits
    s2 = (short)(__builtin_bit_cast(unsigned, r2) >> 16);        // exact bf16
}

// ---------------------------------------------------------------------------
// one-time weight presplits
// ---------------------------------------------------------------------------
__global__ void presplit3_k(const float* __restrict__ src, short* __restrict__ p0,
                            short* __restrict__ p1, short* __restrict__ p2, int n4)
{
    int i = blockIdx.x * 256 + threadIdx.x;
    if (i < n4) {
        float4 v = ((const float4*)src)[i];
        float xs[4] = {v.x, v.y, v.z, v.w};
        short4v a, b, c;
#pragma unroll
        for (int e = 0; e < 4; ++e) { short h, m, l; split3(xs[e], h, m, l); a[e] = h; b[e] = m; c[e] = l; }
        ((short4v*)p0)[i] = a; ((short4v*)p1)[i] = b; ((short4v*)p2)[i] = c;
    }
}

__global__ void presplit2_k(const float* __restrict__ src, short* __restrict__ p0,
                            short* __restrict__ p1, int n4)
{
    int i = blockIdx.x * 256 + threadIdx.x;
    if (i < n4) {
        float4 v = ((const float4*)src)[i];
        float xs[4] = {v.x, v.y, v.z, v.w};
        short4v a, b;
#pragma unroll
        for (int e = 0; e < 4; ++e) { short h, l; split2(xs[e], h, l); a[e] = h; b[e] = l; }
        ((short4v*)p0)[i] = a; ((short4v*)p1)[i] = b;
    }
}

// ---------------------------------------------------------------------------
// QKV GEMM: C = A @ B^T. A fp32 (trunc-split3 in staging), B = 3 presplit
// bf16 planes (pure copies). 128x128 tile, BK=32, 6 terms, hoisted bfr.
// Term order (0,0)(0,1)(0,2)(1,0)(1,1)(2,0) — same as R9.
// ---------------------------------------------------------------------------
__global__ __launch_bounds__(256) void gemm_qkv(
    const float* __restrict__ A,
    const short* __restrict__ B0, const short* __restrict__ B1, const short* __restrict__ B2,
    float* __restrict__ C, int M, int N, int K)
{
    __shared__ short8 As[3][512];   // 24 KB
    __shared__ short8 Bs[3][512];   // 24 KB
    const int t = threadIdx.x;
    const int tile_m = blockIdx.y * 128;
    const int tile_n = blockIdx.x * 128;
    const int wave = t >> 6, lane = t & 63;
    const int quad = lane >> 4, mrow = lane & 15;
    const int wr = (wave >> 1) * 64, wc = (wave & 1) * 64;
    const short* Bp[3] = {B0, B1, B2};

    floatx4 acc[4][4];
#pragma unroll
    for (int i = 0; i < 4; ++i)
#pragma unroll
        for (int j = 0; j < 4; ++j) acc[i][j] = (floatx4){0.f, 0.f, 0.f, 0.f};

    for (int k0 = 0; k0 < K; k0 += 32) {
        __syncthreads();
        // A: trunc-split 8 elements x 2 iterations
#pragma unroll
        for (int s = 0; s < 2; ++s) {
            int g = s * 256 + t;
            int row = g >> 2, q = g & 3;
            int ga = tile_m + row;
            float4 a0 = {0.f, 0.f, 0.f, 0.f}, a1 = {0.f, 0.f, 0.f, 0.f};
            if (ga < M) {
                const float* p = A + (size_t)ga * K + k0 + q * 8;
                a0 = *(const float4*)p;
                a1 = *(const float4*)(p + 4);
            }
            float xs[8] = {a0.x, a0.y, a0.z, a0.w, a1.x, a1.y, a1.z, a1.w};
            short8 v0, v1, v2;
#pragma unroll
            for (int e = 0; e < 8; ++e) {
                short h, m, l; tsplit3(xs[e], h, m, l);
                v0[e] = h; v1[e] = m; v2[e] = l;
            }
            As[0][q * 128 + row] = v0;
            As[1][q * 128 + row] = v1;
            As[2][q * 128 + row] = v2;
        }
        // B: pure copies from planes (no guard: N-grid exact)
#pragma unroll
        for (int s = 0; s < 6; ++s) {
            int g = s * 256 + t;
            int pl = g >> 9, rem = g & 511;
            int row = rem >> 2, q = rem & 3;
            short8 v = *(const short8*)(Bp[pl] + (size_t)(tile_n + row) * K + k0 + q * 8);
            Bs[pl][q * 128 + row] = v;
        }
        __syncthreads();

        short8 bfr[3][4];
#pragma unroll
        for (int tb = 0; tb < 3; ++tb)
#pragma unroll
            for (int j = 0; j < 4; ++j)
                bfr[tb][j] = Bs[tb][quad * 128 + wc + j * 16 + mrow];

#pragma unroll
        for (int ta = 0; ta < 3; ++ta) {
            short8 af[4];
#pragma unroll
            for (int i = 0; i < 4; ++i)
                af[i] = As[ta][quad * 128 + wr + i * 16 + mrow];
            const int ntb = 3 - ta;
#pragma unroll
            for (int tb = 0; tb < 3; ++tb) {
                if (tb >= ntb) break;
#pragma unroll
                for (int i = 0; i < 4; ++i)
#pragma unroll
                    for (int j = 0; j < 4; ++j)
                        acc[i][j] = __builtin_amdgcn_mfma_f32_16x16x32_bf16(af[i], bfr[tb][j], acc[i][j], 0, 0, 0);
            }
        }
    }

#pragma unroll
    for (int i = 0; i < 4; ++i)
#pragma unroll
        for (int r = 0; r < 4; ++r) {
            int grow = tile_m + wr + i * 16 + quad * 4 + r;
            if (grow < M)
#pragma unroll
                for (int j = 0; j < 4; ++j) {
                    int gcol = tile_n + wc + j * 16 + mrow;
                    C[(size_t)grow * N + gcol] = acc[i][j][r];
                }
        }
}

// ---------------------------------------------------------------------------
// Proj GEMM: A = 2 presplit bf16 planes (from attn epilogue), B = 2 presplit
// planes of w_proj. 4 terms in R9 order (ll, lh, hl, hh). + bias.
// ---------------------------------------------------------------------------
__global__ __launch_bounds__(256) void gemm_proj(
    const short* __restrict__ Ah_, const short* __restrict__ Al_,
    const short* __restrict__ Bh_, const short* __restrict__ Bl_,
    const float* __restrict__ bias, float* __restrict__ C, int M, int N, int K)
{
    __shared__ short8 Ah[512], Al[512];
    __shared__ short8 Bh[512], Bl[512];
    const int t = threadIdx.x;
    const int tile_m = blockIdx.y * 128;
    const int tile_n = blockIdx.x * 128;
    const int wave = t >> 6, lane = t & 63;
    const int quad = lane >> 4, mrow = lane & 15;
    const int wr = (wave >> 1) * 64, wc = (wave & 1) * 64;

    floatx4 acc[4][4];
#pragma unroll
    for (int i = 0; i < 4; ++i)
#pragma unroll
        for (int j = 0; j < 4; ++j) acc[i][j] = (floatx4){0.f, 0.f, 0.f, 0.f};

    for (int k0 = 0; k0 < K; k0 += 32) {
        __syncthreads();
#pragma unroll
        for (int s = 0; s < 2; ++s) {
            int g = s * 256 + t;
            int row = g >> 2, q = g & 3;
            int ga = tile_m + row;
            short8 vh = {0,0,0,0,0,0,0,0}, vl = {0,0,0,0,0,0,0,0};
            if (ga < M) {
                vh = *(const short8*)(Ah_ + (size_t)ga * K + k0 + q * 8);
                vl = *(const short8*)(Al_ + (size_t)ga * K + k0 + q * 8);
            }
            Ah[q * 128 + row] = vh;
            Al[q * 128 + row] = vl;
            short8 wh = *(const short8*)(Bh_ + (size_t)(tile_n + row) * K + k0 + q * 8);
            short8 wl = *(const short8*)(Bl_ + (size_t)(tile_n + row) * K + k0 + q * 8);
            Bh[q * 128 + row] = wh;
            Bl[q * 128 + row] = wl;
        }
        __syncthreads();
        short8 ah[4], al[4], bh[4], bl[4];
#pragma unroll
        for (int i = 0; i < 4; ++i) {
            ah[i] = Ah[quad * 128 + wr + i * 16 + mrow];
            al[i] = Al[quad * 128 + wr + i * 16 + mrow];
        }
#pragma unroll
        for (int j = 0; j < 4; ++j) {
            bh[j] = Bh[quad * 128 + wc + j * 16 + mrow];
            bl[j] = Bl[quad * 128 + wc + j * 16 + mrow];
        }
#pragma unroll
        for (int i = 0; i < 4; ++i)
#pragma unroll
            for (int j = 0; j < 4; ++j) {
                acc[i][j] = __builtin_amdgcn_mfma_f32_16x16x32_bf16(al[i], bl[j], acc[i][j], 0, 0, 0);
                acc[i][j] = __builtin_amdgcn_mfma_f32_16x16x32_bf16(al[i], bh[j], acc[i][j], 0, 0, 0);
                acc[i][j] = __builtin_amdgcn_mfma_f32_16x16x32_bf16(ah[i], bl[j], acc[i][j], 0, 0, 0);
                acc[i][j] = __builtin_amdgcn_mfma_f32_16x16x32_bf16(ah[i], bh[j], acc[i][j], 0, 0, 0);
            }
    }

#pragma unroll
    for (int i = 0; i < 4; ++i)
#pragma unroll
        for (int r = 0; r < 4; ++r) {
            int grow = tile_m + wr + i * 16 + quad * 4 + r;
            if (grow < M)
#pragma unroll
                for (int j = 0; j < 4; ++j) {
                    int gcol = tile_n + wc + j * 16 + mrow;
                    C[(size_t)grow * N + gcol] = acc[i][j][r] + bias[gcol];
                }
        }
}

// ---------------------------------------------------------------------------
__global__ __launch_bounds__(256) void quant_stats(
    const float* __restrict__ qkv, float* __restrict__ sqf, float* __restrict__ skf,
    u64* __restrict__ qbits, u64* __restrict__ kbits, float* __restrict__ svf)
{
    const int bh = blockIdx.x;
    const int b = bh / NUM_HEADS, h = bh % NUM_HEADS;
    const int t = threadIdx.x;
    const size_t base = (size_t)b * N_TOK * QKV_COLS + h * 64;
    __shared__ double red[256];
    __shared__ float redf[256];

    const int d = t & 63;
    double aq = 0.0, ak = 0.0;
    for (int i = t; i < N_TOK * 64; i += 256) {
        int n = i >> 6;
        size_t off = base + (size_t)n * QKV_COLS + d;
        aq += (double)fabsf(qkv[off]);
        ak += (double)fabsf(qkv[off + C_DIM]);
    }
    red[t] = aq; __syncthreads();
    for (int s = 128; s > 0; s >>= 1) { if (t < s) red[t] += red[t + s]; __syncthreads(); }
    if (t == 0) sqf[bh] = (float)(red[0] / 12608.0);
    __syncthreads();
    red[t] = ak; __syncthreads();
    for (int s = 128; s > 0; s >>= 1) { if (t < s) red[t] += red[t + s]; __syncthreads(); }
    if (t == 0) skf[bh] = (float)(red[0] / 12608.0);
    __syncthreads();

    float vm = 0.f;
    for (int n = (t >> 6); n < N_TOK; n += 4)
        vm = fmaxf(vm, fabsf(qkv[base + (size_t)n * QKV_COLS + 2 * C_DIM + d]));
    redf[t] = vm; __syncthreads();
    if (t < 64) {
        float m4 = fmaxf(fmaxf(redf[t], redf[t + 64]), fmaxf(redf[t + 128], redf[t + 192]));
        svf[bh * 64 + t] = 127.0f / (m4 + 1e-6f);
    }

    const int wave = t >> 6, lane = t & 63;
    for (int n = wave; n < N_TOK; n += 4) {
        size_t off = base + (size_t)n * QKV_COLS + lane;
        u64 bq = __ballot(qkv[off] >= 0.f);
        u64 bk = __ballot(qkv[off + C_DIM] >= 0.f);
        if (lane == 0) { qbits[bh * N_TOK + n] = bq; kbits[bh * N_TOK + n] = bk; }
    }
}

__global__ void detect_rel64(const int* __restrict__ rel, int* __restrict__ flag)
{
    __shared__ int nz;
    if (threadIdx.x == 0) nz = 0;
    __syncthreads();
    int local = 0;
    for (int i = threadIdx.x; i < NN / 2; i += 256)
        if (rel[2 * i + 1] != 0) local = 1;
    if (local) atomicOr(&nz, 1);
    __syncthreads();
    if (threadIdx.x == 0) flag[0] = (nz == 0) ? 1 : 0;
}

__global__ void build_bias(const float* __restrict__ rpb, const int* __restrict__ rel,
                           const int* __restrict__ flag, float* __restrict__ bias_f)
{
    int nm = blockIdx.x * 256 + threadIdx.x;
    int h = blockIdx.y;
    if (nm < NN) {
        int idx = flag[0] ? rel[2 * nm] : rel[nm];
        bias_f[(size_t)h * NN + nm] = rpb[idx * NUM_HEADS + h];
    }
}

// ---------------------------------------------------------------------------
// Fused attention with MFMA P@V (R9-proven). Epilogue now writes split2
// hi/lo bf16 planes (bit-identical to R9 proj's staging of the fp32 value).
// ---------------------------------------------------------------------------
__global__ __launch_bounds__(256) void attn_mfma(
    const float* __restrict__ qkv, const float* __restrict__ sqf, const float* __restrict__ skf,
    const u64* __restrict__ qbits, const u64* __restrict__ kbits,
    const float* __restrict__ svf, const float* __restrict__ bias_f,
    short* __restrict__ aoh, short* __restrict__ aol)
{
    const int bh = blockIdx.x;
    const int b = bh / NUM_HEADS, h = bh % NUM_HEADS;
    const int t = threadIdx.x;
    const int wave = t >> 6, lane = t & 63;
    const int quad = lane >> 4, mrow = lane & 15;

    __shared__ __align__(16) short vth[64 * VT_PITCH];
    __shared__ __align__(16) short vtl[64 * VT_PITCH];
    __shared__ __align__(16) short pbuf[2][16 * VT_PITCH];
    __shared__ u64 qb[N_TOK], kb[N_TOK];

    for (int i = t; i < N_TOK; i += 256) {
        qb[i] = qbits[bh * N_TOK + i];
        kb[i] = kbits[bh * N_TOK + i];
    }

    const size_t vbase = (size_t)b * N_TOK * QKV_COLS + 2 * C_DIM + h * 64;
    const int d0 = t & 63;
    const float sv = svf[bh * 64 + d0];
    const float inv_sv = sv + 1e-6f;
    for (int i = t; i < N_TOK * 64; i += 256) {
        int n = i >> 6;
        float v = qkv[vbase + (size_t)n * QKV_COLS + d0];
        float vqf = rintf(v * sv) / inv_sv;
        short hh, ll; split2(vqf, hh, ll);
        vth[d0 * VT_PITCH + n] = hh;
        vtl[d0 * VT_PITCH + n] = ll;
    }
    for (int i = t; i < 64 * (VT_PITCH - N_TOK); i += 256) {
        int d = i / (VT_PITCH - N_TOK), n = N_TOK + i % (VT_PITCH - N_TOK);
        vth[d * VT_PITCH + n] = 0;
        vtl[d * VT_PITCH + n] = 0;
    }
    __syncthreads();

    const int ct = wave;
    short8 bfh[7], bfl[7];
#pragma unroll
    for (int kt = 0; kt < 7; ++kt) {
        int off = (ct * 16 + mrow) * VT_PITCH + kt * 32 + quad * 8;
        bfh[kt] = *(const short8*)&vth[off];
        bfl[kt] = *(const short8*)&vtl[off];
    }

    const float cf = sqf[bh] * skf[bh] * 0.125f;
    const float* bh_bias = bias_f + (size_t)h * NN;
    const float qs = 1.0f / 255.0f;

    auto computeP = [&](int strip, int buf) {
        short* pb = &pbuf[buf][0];
#pragma unroll
        for (int rr = 0; rr < 4; ++rr) {
            int nl = wave * 4 + rr;
            int n = strip * 16 + nl;
            short* prow = pb + nl * VT_PITCH;
            int m0 = lane, m1 = 64 + lane, m2 = 128 + lane, m3 = 192 + lane;
            if (n < N_TOK) {
                const u64 qn = qb[n];
                const float* brow = bh_bias + (size_t)n * N_TOK;
                float l0 = cf * (float)(64 - 2 * (int)__popcll(qn ^ kb[m0])) + brow[m0];
                float l1 = cf * (float)(64 - 2 * (int)__popcll(qn ^ kb[m1])) + brow[m1];
                float l2 = cf * (float)(64 - 2 * (int)__popcll(qn ^ kb[m2])) + brow[m2];
                float l3 = -1e30f;
                if (m3 < N_TOK)
                    l3 = cf * (float)(64 - 2 * (int)__popcll(qn ^ kb[m3])) + brow[m3];
                float mx = fmaxf(fmaxf(l0, l1), fmaxf(l2, l3));
#pragma unroll
                for (int off = 32; off > 0; off >>= 1) mx = fmaxf(mx, __shfl_xor(mx, off, 64));
                float e0 = expf(l0 - mx), e1 = expf(l1 - mx), e2 = expf(l2 - mx);
                float e3 = (m3 < N_TOK) ? expf(l3 - mx) : 0.f;
                float sum = e0 + e1 + e2 + e3;
#pragma unroll
                for (int off = 32; off > 0; off >>= 1) sum += __shfl_xor(sum, off, 64);
                float inv = 1.0f / sum;
                float p0 = fminf(rintf((e0 * inv) / qs), 255.f);
                float p1 = fminf(rintf((e1 * inv) / qs), 255.f);
                float p2 = fminf(rintf((e2 * inv) / qs), 255.f);
                float p3 = fminf(rintf((e3 * inv) / qs), 255.f);
                prow[m0] = __builtin_bit_cast(short, __float2bfloat16(p0));
                prow[m1] = __builtin_bit_cast(short, __float2bfloat16(p1));
                prow[m2] = __builtin_bit_cast(short, __float2bfloat16(p2));
                if (m3 < VT_PITCH)
                    prow[m3] = __builtin_bit_cast(short, __float2bfloat16(p3));
            } else {
                prow[m0] = 0; prow[m1] = 0; prow[m2] = 0;
                if (m3 < VT_PITCH) prow[m3] = 0;
            }
        }
    };

    computeP(0, 0);
    __syncthreads();

    for (int strip = 0; strip < 13; ++strip) {
        if (strip + 1 < 13) computeP(strip + 1, (strip + 1) & 1);

        const short* pb = &pbuf[strip & 1][0];
        floatx4 acc = (floatx4){0.f, 0.f, 0.f, 0.f};
#pragma unroll
        for (int kt = 0; kt < 7; ++kt) {
            short8 af = *(const short8*)&pb[mrow * VT_PITCH + kt * 32 + quad * 8];
            acc = __builtin_amdgcn_mfma_f32_16x16x32_bf16(af, bfh[kt], acc, 0, 0, 0);
            acc = __builtin_amdgcn_mfma_f32_16x16x32_bf16(af, bfl[kt], acc, 0, 0, 0);
        }
#pragma unroll
        for (int r = 0; r < 4; ++r) {
            int n = strip * 16 + quad * 4 + r;
            if (n < N_TOK) {
                size_t o = ((size_t)(b * N_TOK + n)) * C_DIM + h * 64 + ct * 16 + mrow;
                short hh, ll; split2(qs * acc[r], hh, ll);
                aoh[o] = hh; aol[o] = ll;
            }
        }
        __syncthreads();
    }
}

// ---------------------------------------------------------------------------
extern "C" void kernel_launch(void* const* d_in, const int* in_sizes, int n_in,
                              void* d_out, int out_size, void* d_ws, size_t ws_size,
                              hipStream_t stream)
{
    const float* x      = (const float*)d_in[0];
    const float* w_qkv  = (const float*)d_in[1];
    const float* w_proj = (const float*)d_in[2];
    const float* b_proj = (const float*)d_in[3];
    const float* rpb    = (const float*)d_in[4];
    const int*   rel    = (const int*)d_in[5];
    float* out = (float*)d_out;

    char* ws = (char*)d_ws;
    float* qkv   = (float*)ws; ws += (size_t)M_ROWS * QKV_COLS * sizeof(float);      // 116.2 MB
    short* wq0   = (short*)ws; ws += (size_t)QKV_COLS * C_DIM * sizeof(short);       // 3.54 MB
    short* wq1   = (short*)ws; ws += (size_t)QKV_COLS * C_DIM * sizeof(short);
    short* wq2   = (short*)ws; ws += (size_t)QKV_COLS * C_DIM * sizeof(short);
    short* wph   = (short*)ws; ws += (size_t)C_DIM * C_DIM * sizeof(short);          // 1.18 MB
    short* wpl   = (short*)ws; ws += (size_t)C_DIM * C_DIM * sizeof(short);
    short* aoh   = (short*)ws; ws += (size_t)M_ROWS * C_DIM * sizeof(short);         // 19.4 MB
    short* aol   = (short*)ws; ws += (size_t)M_ROWS * C_DIM * sizeof(short);
    float* bias_f= (float*)ws; ws += (size_t)NUM_HEADS * NN * sizeof(float);         // 1.86 MB
    float* sqf   = (float*)ws; ws += 768 * sizeof(float);
    float* skf   = (float*)ws; ws += 768 * sizeof(float);
    float* svf   = (float*)ws; ws += 768 * 64 * sizeof(float);
    u64* qbits   = (u64*)ws;   ws += (size_t)768 * N_TOK * sizeof(u64);
    u64* kbits   = (u64*)ws;   ws += (size_t)768 * N_TOK * sizeof(u64);
    int* flag    = (int*)ws;   ws += 256;
    // total ~171 MB

    detect_rel64<<<1, 256, 0, stream>>>(rel, flag);

    // one-time weight presplits
    presplit3_k<<<(QKV_COLS * C_DIM / 4 + 255) / 256, 256, 0, stream>>>(w_qkv, wq0, wq1, wq2, QKV_COLS * C_DIM / 4);
    presplit2_k<<<(C_DIM * C_DIM / 4 + 255) / 256, 256, 0, stream>>>(w_proj, wph, wpl, C_DIM * C_DIM / 4);

    // 1) QKV = x @ w_qkv^T
    gemm_qkv<<<dim3(QKV_COLS / 128, (M_ROWS + 127) / 128), 256, 0, stream>>>(
        x, wq0, wq1, wq2, qkv, M_ROWS, QKV_COLS, C_DIM);

    quant_stats<<<768, 256, 0, stream>>>(qkv, sqf, skf, qbits, kbits, svf);

    build_bias<<<dim3((NN + 255) / 256, NUM_HEADS), 256, 0, stream>>>(rpb, rel, flag, bias_f);

    attn_mfma<<<768, 256, 0, stream>>>(qkv, sqf, skf, qbits, kbits, svf, bias_f, aoh, aol);

    // 5) out = attn_o @ w_proj^T + b_proj
    gemm_proj<<<dim3(C_DIM / 128, (M_ROWS + 127) / 128), 256, 0, stream>>>(
        aoh, aol, wph, wpl, b_proj, out, M_ROWS, C_DIM, C_DIM);
}